// Round 2
// baseline (327.454 us; speedup 1.0000x reference)
//
#include <hip/hip_runtime.h>
#include <math.h>
#include <stdint.h>

#define B_ 64
#define J_ 512
#define D_ 1024

typedef __attribute__((ext_vector_type(8))) short short8;
typedef __attribute__((ext_vector_type(4))) float f32x4;

#define GLOBAL_AS __attribute__((address_space(1)))
#define LDS_AS    __attribute__((address_space(3)))

__device__ __forceinline__ void async16(const void* g, void* l) {
    __builtin_amdgcn_global_load_lds((const GLOBAL_AS uint32_t*)g,
                                     (LDS_AS uint32_t*)l, 16, 0, 0);
}

// tanh(x) = 1 - 2/(1+e^{2x}); saturates correctly for |x| large.
__device__ __forceinline__ float fast_tanh(float x) {
    return 1.0f - 2.0f / (1.0f + __expf(2.0f * x));
}

// fp32 -> bf16 round-to-nearest-even
__device__ __forceinline__ unsigned short f2bf(float f) {
    uint32_t u = __builtin_bit_cast(uint32_t, f);
    u += 0x7fffu + ((u >> 16) & 1u);
    return (unsigned short)(u >> 16);
}

__device__ __forceinline__ uint32_t pk2(float a, float b) {
    return (uint32_t)f2bf(a) | ((uint32_t)f2bf(b) << 16);
}

// ---------------------------------------------------------------------------
// prep: W1[k][n] fp32 -> W1t[n][k] bf16, fused with zeroing of pooled accum.
// Replaces transpose_cast_w1 + hipMemsetAsync (one dispatch instead of two).
// ---------------------------------------------------------------------------
__global__ __launch_bounds__(256) void prep_kernel(const float* __restrict__ W1,
                                                   unsigned short* __restrict__ W1t,
                                                   float* __restrict__ pooled) {
    __shared__ float t[32][33];
    const int b   = blockIdx.x;
    const int tid = threadIdx.x;
    if (b < 256) pooled[b * 256 + tid] = 0.f;   // 64*1024 floats total
    const int bx = b & 31, by = b >> 5;
    const int tx = tid & 31, ty = tid >> 5;
    const int n = bx * 32 + tx;
    for (int i = ty; i < 32; i += 8)
        t[i][tx] = W1[(size_t)(by * 32 + i) * D_ + n];
    __syncthreads();
    const int k = by * 32 + tx;
    for (int i = ty; i < 32; i += 8)
        W1t[(size_t)(bx * 32 + i) * D_ + k] = f2bf(t[tx][i]);
}

// ---------------------------------------------------------------------------
// Fused cast+gemm+score kernel.
// Block: 256 threads (4 waves), tile 64(M) x 256(N) per n0-step, BK=64,
// wave grid 1x4 over N (wave-tile 64x64 -> 512 B LDS-read per MFMA).
// Double-buffered B via global_load_lds prefetched ACROSS the single
// __syncthreads per iteration; A reg-staged (ds_write + raw barrier).
// First n0 pass loads A from f32 x, packs to bf16 in the MFMA shadow and
// writes through to Xb; later passes re-read bf16 Xb (self-written rows).
// ---------------------------------------------------------------------------
__global__ __launch_bounds__(256, 2) void gemm_score_kernel(
    const float* __restrict__ x, unsigned short* __restrict__ Xb,
    const unsigned short* __restrict__ W1t,
    const float* __restrict__ b1, const float* __restrict__ W2,
    const float* __restrict__ b2, const float* __restrict__ mask,
    float* __restrict__ val_ws, float* __restrict__ pooled)
{
    __shared__ __align__(16) unsigned short ldsA[64 * 64];        // 8 KB, single
    __shared__ __align__(16) unsigned short ldsB[2 * 256 * 64];   // 64 KB dbuf

    const int tid  = threadIdx.x;
    const int wave = tid >> 6;        // 0..3 (N-dim)
    const int l    = tid & 63;
    const int l15  = l & 15;
    const int kgrp = l >> 4;
    const int l7   = l & 7;
    const int r0   = blockIdx.x * 64; // 64 rows per block, within one batch
    const int bb   = r0 >> 9;

    // --- A staging: 2 swizzled 16B chunks per thread (f = tid + t*256) ---
    const float* gAx[2];
    unsigned short* gXb[2];
    int lAoff[2];
    #pragma unroll
    for (int t = 0; t < 2; ++t) {
        const int f   = tid + t * 256;
        const int row = f >> 3;
        const int ch  = ((f & 7) ^ (row & 7)) << 3;   // swizzled k-chunk (elems)
        gAx[t]   = x  + (size_t)(r0 + row) * D_ + ch;
        gXb[t]   = Xb + (size_t)(r0 + row) * D_ + ch;
        lAoff[t] = f * 8;                              // ushort units
    }

    // --- B staging via global_load_lds: 8 chunks/thread, wave-uniform LDS base ---
    const unsigned short* gB[8];
    unsigned short* lB[8];
    #pragma unroll
    for (int t = 0; t < 8; ++t) {
        const int f   = tid + t * 256;
        const int row = f >> 3;
        const int ch  = ((f & 7) ^ (row & 7)) << 3;
        gB[t] = W1t + (size_t)row * D_ + ch;
        lB[t] = ldsB + t * 2048 + (wave << 9);         // lane*16B added by HW
    }

    // --- fragment LDS offsets (ushort units), swizzle-consistent ---
    int aoff[4][2], boff[4][2];
    #pragma unroll
    for (int mi = 0; mi < 4; ++mi)
        #pragma unroll
        for (int ks = 0; ks < 2; ++ks)
            aoff[mi][ks] = (mi * 16 + l15) * 64 + (((ks * 4 + kgrp) ^ l7) << 3);
    #pragma unroll
    for (int ni = 0; ni < 4; ++ni)
        #pragma unroll
        for (int ks = 0; ks < 2; ++ks)
            boff[ni][ks] = (wave * 64 + ni * 16 + l15) * 64 + (((ks * 4 + kgrp) ^ l7) << 3);

    float pv[4][4];
    #pragma unroll
    for (int mi = 0; mi < 4; ++mi)
        #pragma unroll
        for (int r = 0; r < 4; ++r) pv[mi][r] = 0.f;

    f32x4 acc[4][4];
    #pragma unroll
    for (int mi = 0; mi < 4; ++mi)
        #pragma unroll
        for (int ni = 0; ni < 4; ++ni)
            acc[mi][ni] = (f32x4){0.f, 0.f, 0.f, 0.f};

    // --- prologue: A[0] from f32 x (pack now); B[0] async into buf 0 ---
    uint4 curA0, curA1;
    {
        const float4 p0 = *reinterpret_cast<const float4*>(gAx[0]);
        const float4 p1 = *reinterpret_cast<const float4*>(gAx[0] + 4);
        const float4 p2 = *reinterpret_cast<const float4*>(gAx[1]);
        const float4 p3 = *reinterpret_cast<const float4*>(gAx[1] + 4);
        curA0 = (uint4){pk2(p0.x, p0.y), pk2(p0.z, p0.w), pk2(p1.x, p1.y), pk2(p1.z, p1.w)};
        curA1 = (uint4){pk2(p2.x, p2.y), pk2(p2.z, p2.w), pk2(p3.x, p3.y), pk2(p3.z, p3.w)};
    }
    #pragma unroll
    for (int t = 0; t < 8; ++t) async16(gB[t], lB[t]);

    float4 fa0, fa1, fa2, fa3;   // f32 prefetch (n0==0 path)
    uint4 nxA0, nxA1;            // bf16 prefetch (n0>=1 path)

    // 64 flat iterations: n0 = it>>4, k0 = (it&15)*64
    for (int it = 0; it < 64; ++it) {
        const int cur = it & 1;

        // X barrier: drains vmcnt(0) -> B[it] landed in buf[cur]; all waves
        // done reading ldsA and buf[cur^1] (WAR-safe for publish + prefetch).
        __syncthreads();

        // publish A[it]; first n0 pass also writes through to Xb
        *reinterpret_cast<uint4*>(ldsA + lAoff[0]) = curA0;
        *reinterpret_cast<uint4*>(ldsA + lAoff[1]) = curA1;
        if (it < 16) {
            const int k0 = it << 6;
            *reinterpret_cast<uint4*>(gXb[0] + k0) = curA0;
            *reinterpret_cast<uint4*>(gXb[1] + k0) = curA1;
        }

        // prefetch it+1: A -> regs, B -> buf[cur^1] (stays in flight across Y)
        const int nit = it + 1;
        if (nit < 64) {
            const int ak0 = (nit & 15) << 6;
            if (nit < 16) {
                fa0 = *reinterpret_cast<const float4*>(gAx[0] + ak0);
                fa1 = *reinterpret_cast<const float4*>(gAx[0] + ak0 + 4);
                fa2 = *reinterpret_cast<const float4*>(gAx[1] + ak0);
                fa3 = *reinterpret_cast<const float4*>(gAx[1] + ak0 + 4);
            } else {
                nxA0 = *reinterpret_cast<const uint4*>(gXb[0] + ak0);
                nxA1 = *reinterpret_cast<const uint4*>(gXb[1] + ak0);
            }
            const size_t bofs = (size_t)(nit >> 4) * 256 * D_ + ak0;
            const int nb = (cur ^ 1) << 14;   // other buffer (ushort offset)
            #pragma unroll
            for (int t = 0; t < 8; ++t) async16(gB[t] + bofs, lB[t] + nb);
        }

        // Y barrier: A ds_writes visible; vmcnt NOT drained (B[it+1] in flight)
        asm volatile("s_waitcnt lgkmcnt(0)" ::: "memory");
        __builtin_amdgcn_s_barrier();
        asm volatile("" ::: "memory");

        const int bo = cur << 14;
        __builtin_amdgcn_s_setprio(1);
        #pragma unroll
        for (int ks = 0; ks < 2; ++ks) {
            short8 a0 = *reinterpret_cast<const short8*>(ldsA + aoff[0][ks]);
            short8 a1 = *reinterpret_cast<const short8*>(ldsA + aoff[1][ks]);
            short8 a2 = *reinterpret_cast<const short8*>(ldsA + aoff[2][ks]);
            short8 a3 = *reinterpret_cast<const short8*>(ldsA + aoff[3][ks]);
            short8 b0 = *reinterpret_cast<const short8*>(ldsB + bo + boff[0][ks]);
            short8 b1f = *reinterpret_cast<const short8*>(ldsB + bo + boff[1][ks]);
            short8 b2f = *reinterpret_cast<const short8*>(ldsB + bo + boff[2][ks]);
            short8 b3f = *reinterpret_cast<const short8*>(ldsB + bo + boff[3][ks]);
            acc[0][0] = __builtin_amdgcn_mfma_f32_16x16x32_bf16(a0, b0,  acc[0][0], 0, 0, 0);
            acc[1][0] = __builtin_amdgcn_mfma_f32_16x16x32_bf16(a1, b0,  acc[1][0], 0, 0, 0);
            acc[2][0] = __builtin_amdgcn_mfma_f32_16x16x32_bf16(a2, b0,  acc[2][0], 0, 0, 0);
            acc[3][0] = __builtin_amdgcn_mfma_f32_16x16x32_bf16(a3, b0,  acc[3][0], 0, 0, 0);
            acc[0][1] = __builtin_amdgcn_mfma_f32_16x16x32_bf16(a0, b1f, acc[0][1], 0, 0, 0);
            acc[1][1] = __builtin_amdgcn_mfma_f32_16x16x32_bf16(a1, b1f, acc[1][1], 0, 0, 0);
            acc[2][1] = __builtin_amdgcn_mfma_f32_16x16x32_bf16(a2, b1f, acc[2][1], 0, 0, 0);
            acc[3][1] = __builtin_amdgcn_mfma_f32_16x16x32_bf16(a3, b1f, acc[3][1], 0, 0, 0);
            acc[0][2] = __builtin_amdgcn_mfma_f32_16x16x32_bf16(a0, b2f, acc[0][2], 0, 0, 0);
            acc[1][2] = __builtin_amdgcn_mfma_f32_16x16x32_bf16(a1, b2f, acc[1][2], 0, 0, 0);
            acc[2][2] = __builtin_amdgcn_mfma_f32_16x16x32_bf16(a2, b2f, acc[2][2], 0, 0, 0);
            acc[3][2] = __builtin_amdgcn_mfma_f32_16x16x32_bf16(a3, b2f, acc[3][2], 0, 0, 0);
            acc[0][3] = __builtin_amdgcn_mfma_f32_16x16x32_bf16(a0, b3f, acc[0][3], 0, 0, 0);
            acc[1][3] = __builtin_amdgcn_mfma_f32_16x16x32_bf16(a1, b3f, acc[1][3], 0, 0, 0);
            acc[2][3] = __builtin_amdgcn_mfma_f32_16x16x32_bf16(a2, b3f, acc[2][3], 0, 0, 0);
            acc[3][3] = __builtin_amdgcn_mfma_f32_16x16x32_bf16(a3, b3f, acc[3][3], 0, 0, 0);
        }
        __builtin_amdgcn_s_setprio(0);

        // finish A prefetch in the MFMA shadow (pack or move)
        if (nit < 64) {
            if (nit < 16) {
                curA0 = (uint4){pk2(fa0.x, fa0.y), pk2(fa0.z, fa0.w),
                                pk2(fa1.x, fa1.y), pk2(fa1.z, fa1.w)};
                curA1 = (uint4){pk2(fa2.x, fa2.y), pk2(fa2.z, fa2.w),
                                pk2(fa3.x, fa3.y), pk2(fa3.z, fa3.w)};
            } else {
                curA0 = nxA0;
                curA1 = nxA1;
            }
        }

        // n0-tile boundary: fold this 256-col tile of h into pv, reset acc
        if ((it & 15) == 15) {
            const int n0 = it >> 4;
            #pragma unroll
            for (int ni = 0; ni < 4; ++ni) {
                const int col = n0 * 256 + wave * 64 + ni * 16 + l15;
                const float b1v = b1[col];
                const float w2v = W2[col];
                #pragma unroll
                for (int mi = 0; mi < 4; ++mi)
                    #pragma unroll
                    for (int r = 0; r < 4; ++r) {
                        const float h = fast_tanh(acc[mi][ni][r] + b1v);
                        pv[mi][r] = fmaf(h, w2v, pv[mi][r]);
                        acc[mi][ni][r] = 0.f;
                    }
            }
        }
    }

    // epilogue scratch aliases onto ldsA (done with MFMA reads after barrier)
    __syncthreads();
    float* pv_part = reinterpret_cast<float*>(ldsA);   // [4][64]
    float* vrow    = pv_part + 256;                    // [64]

    // reduce pv over the 16 col-lanes (C/D: row = kgrp*4+r, col-group = l15)
    #pragma unroll
    for (int mi = 0; mi < 4; ++mi)
        #pragma unroll
        for (int r = 0; r < 4; ++r) {
            float s = pv[mi][r];
            s += __shfl_xor(s, 1);
            s += __shfl_xor(s, 2);
            s += __shfl_xor(s, 4);
            s += __shfl_xor(s, 8);
            if (l15 == 0) pv_part[wave * 64 + mi * 16 + kgrp * 4 + r] = s;
        }
    __syncthreads();
    if (tid < 64) {
        const float s = b2[0] + pv_part[tid] + pv_part[64 + tid]
                      + pv_part[128 + tid] + pv_part[192 + tid];
        const float sg = 1.0f / (1.0f + __expf(-s));
        const float v = sg * mask[r0 + tid];
        val_ws[r0 + tid] = v;
        vrow[tid] = v;
    }
    __syncthreads();

    // unnormalized pooled: pooled[bb][k] += sum_rows Xb[r][k]*val[r]
    const int kc = tid << 2;
    float a0 = 0.f, a1 = 0.f, a2 = 0.f, a3 = 0.f;
    for (int row = 0; row < 64; ++row) {
        const float v = vrow[row];
        const uint2 u = *reinterpret_cast<const uint2*>(
            Xb + (size_t)(r0 + row) * D_ + kc);
        a0 = fmaf(__builtin_bit_cast(float, u.x << 16), v, a0);
        a1 = fmaf(__builtin_bit_cast(float, u.x & 0xffff0000u), v, a1);
        a2 = fmaf(__builtin_bit_cast(float, u.y << 16), v, a2);
        a3 = fmaf(__builtin_bit_cast(float, u.y & 0xffff0000u), v, a3);
    }
    float* pb = &pooled[bb * D_ + kc];
    atomicAdd(pb + 0, a0);
    atomicAdd(pb + 1, a1);
    atomicAdd(pb + 2, a2);
    atomicAdd(pb + 3, a3);
}

// ---------------------------------------------------------------------------
// Fallback fp32 path (used only if ws too small)
// ---------------------------------------------------------------------------
#define MT 64
#define KT 32
#define PAD 68

__global__ __launch_bounds__(256) void score_kernel_fp32(
    const float* __restrict__ x, const float* __restrict__ mask,
    const float* __restrict__ W1, const float* __restrict__ b1,
    const float* __restrict__ W2, const float* __restrict__ b2,
    float* __restrict__ val_ws, float* __restrict__ pooled)
{
    __shared__ float As[KT][PAD];
    __shared__ float Bs[KT][PAD];
    __shared__ float red[MT][17];
    __shared__ float vrow[MT];

    const int tid = threadIdx.x;
    const int tx = tid & 15;
    const int ty = tid >> 4;
    const int r0 = blockIdx.x * MT;
    const int b  = r0 >> 9;

    float pv[4] = {0.f, 0.f, 0.f, 0.f};

    for (int n0 = 0; n0 < D_; n0 += 64) {
        float acc[4][4];
        #pragma unroll
        for (int i = 0; i < 4; ++i)
            #pragma unroll
            for (int j = 0; j < 4; ++j) acc[i][j] = 0.f;

        for (int k0 = 0; k0 < D_; k0 += KT) {
            #pragma unroll
            for (int ll = 0; ll < 2; ++ll) {
                const int f   = tid + ll * 256;
                const int row = f >> 3;
                const int k4  = (f & 7) << 2;
                const float4 xv = *reinterpret_cast<const float4*>(
                    &x[(size_t)(r0 + row) * D_ + k0 + k4]);
                As[k4 + 0][row] = xv.x;
                As[k4 + 1][row] = xv.y;
                As[k4 + 2][row] = xv.z;
                As[k4 + 3][row] = xv.w;
            }
            #pragma unroll
            for (int ll = 0; ll < 2; ++ll) {
                const int f  = tid + ll * 256;
                const int k  = f >> 4;
                const int n4 = (f & 15) << 2;
                const float4 wv = *reinterpret_cast<const float4*>(
                    &W1[(size_t)(k0 + k) * D_ + n0 + n4]);
                *reinterpret_cast<float4*>(&Bs[k][n4]) = wv;
            }
            __syncthreads();
            #pragma unroll
            for (int kk = 0; kk < KT; ++kk) {
                const float4 a4 = *reinterpret_cast<const float4*>(&As[kk][ty << 2]);
                const float4 b4 = *reinterpret_cast<const float4*>(&Bs[kk][tx << 2]);
                const float av[4] = {a4.x, a4.y, a4.z, a4.w};
                const float bv[4] = {b4.x, b4.y, b4.z, b4.w};
                #pragma unroll
                for (int i = 0; i < 4; ++i)
                    #pragma unroll
                    for (int j = 0; j < 4; ++j)
                        acc[i][j] = fmaf(av[i], bv[j], acc[i][j]);
            }
            __syncthreads();
        }
        #pragma unroll
        for (int j = 0; j < 4; ++j) {
            const int col = n0 + (tx << 2) + j;
            const float b1v = b1[col];
            const float w2v = W2[col];
            #pragma unroll
            for (int i = 0; i < 4; ++i) {
                const float h = fast_tanh(acc[i][j] + b1v);
                pv[i] = fmaf(h, w2v, pv[i]);
            }
        }
    }

    #pragma unroll
    for (int i = 0; i < 4; ++i) red[(ty << 2) + i][tx] = pv[i];
    __syncthreads();

    if (tid < MT) {
        float s = 0.f;
        #pragma unroll
        for (int t = 0; t < 16; ++t) s += red[tid][t];
        const float z  = s + b2[0];
        const float sg = 1.0f / (1.0f + __expf(-z));
        const float v  = sg * mask[r0 + tid];
        val_ws[r0 + tid] = v;
        vrow[tid] = v;
    }
    __syncthreads();

    const int k = tid << 2;
    float a0 = 0.f, a1 = 0.f, a2 = 0.f, a3 = 0.f;
    for (int row = 0; row < MT; ++row) {
        const float v = vrow[row];
        const float4 xv = *reinterpret_cast<const float4*>(
            &x[(size_t)(r0 + row) * D_ + k]);
        a0 = fmaf(xv.x, v, a0);
        a1 = fmaf(xv.y, v, a1);
        a2 = fmaf(xv.z, v, a2);
        a3 = fmaf(xv.w, v, a3);
    }
    float* pb = &pooled[b * D_ + k];
    atomicAdd(pb + 0, a0);
    atomicAdd(pb + 1, a1);
    atomicAdd(pb + 2, a2);
    atomicAdd(pb + 3, a3);
}

__global__ __launch_bounds__(256) void finalize_kernel(
    const float* __restrict__ val_ws, const float* __restrict__ pooled,
    const float* __restrict__ W3, const float* __restrict__ b3,
    float* __restrict__ out)
{
    __shared__ float sred[256];
    const int b = blockIdx.x;
    const int tid = threadIdx.x;

    const float v0 = val_ws[b * J_ + tid];
    const float v1 = val_ws[b * J_ + 256 + tid];
    sred[tid] = v0 + v1;
    __syncthreads();
    for (int s = 128; s > 0; s >>= 1) {
        if (tid < s) sred[tid] += sred[tid + s];
        __syncthreads();
    }
    const float inv = 1.0f / sred[0];

    out[192 + b * J_ + tid]       = v0 * inv;
    out[192 + b * J_ + 256 + tid] = v1 * inv;

    const int k = tid << 2;
    float acc3[3] = {0.f, 0.f, 0.f};
    #pragma unroll
    for (int c = 0; c < 4; ++c) {
        const float p = pooled[b * D_ + k + c] * inv;
        acc3[0] = fmaf(p, W3[(k + c) * 3 + 0], acc3[0]);
        acc3[1] = fmaf(p, W3[(k + c) * 3 + 1], acc3[1]);
        acc3[2] = fmaf(p, W3[(k + c) * 3 + 2], acc3[2]);
    }
    for (int o = 0; o < 3; ++o) {
        __syncthreads();
        sred[tid] = acc3[o];
        __syncthreads();
        for (int s = 128; s > 0; s >>= 1) {
            if (tid < s) sred[tid] += sred[tid + s];
            __syncthreads();
        }
        if (tid == 0) out[b * 3 + o] = sred[0] + b3[o];
    }
}

extern "C" void kernel_launch(void* const* d_in, const int* in_sizes, int n_in,
                              void* d_out, int out_size, void* d_ws, size_t ws_size,
                              hipStream_t stream) {
    const float* x    = (const float*)d_in[0];
    const float* mask = (const float*)d_in[1];
    const float* W1   = (const float*)d_in[2];
    const float* b1   = (const float*)d_in[3];
    const float* W2   = (const float*)d_in[4];
    const float* b2   = (const float*)d_in[5];
    const float* W3   = (const float*)d_in[6];
    const float* b3   = (const float*)d_in[7];
    float* out = (float*)d_out;

    const size_t XB_BYTES   = (size_t)B_ * J_ * D_ * 2;   // 67,108,864
    const size_t W1T_BYTES  = (size_t)D_ * D_ * 2;        //  2,097,152
    const size_t VAL_BYTES  = (size_t)B_ * J_ * 4;        //    131,072
    const size_t POOL_BYTES = (size_t)B_ * D_ * 4;        //    262,144
    const size_t NEED = XB_BYTES + W1T_BYTES + VAL_BYTES + POOL_BYTES;

    if (ws_size >= NEED) {
        unsigned short* Xb  = (unsigned short*)d_ws;
        unsigned short* W1t = (unsigned short*)((char*)d_ws + XB_BYTES);
        float* val_ws = (float*)((char*)d_ws + XB_BYTES + W1T_BYTES);
        float* pooled = (float*)((char*)d_ws + XB_BYTES + W1T_BYTES + VAL_BYTES);

        prep_kernel<<<1024, 256, 0, stream>>>(W1, W1t, pooled);
        gemm_score_kernel<<<512, 256, 0, stream>>>(x, Xb, W1t, b1, W2, b2, mask,
                                                   val_ws, pooled);
        finalize_kernel<<<B_, 256, 0, stream>>>(val_ws, pooled, W3, b3, out);
    } else {
        float* val_ws = (float*)d_ws;
        float* pooled = val_ws + B_ * J_;
        hipMemsetAsync(pooled, 0, POOL_BYTES, stream);
        score_kernel_fp32<<<(B_ * J_) / MT, 256, 0, stream>>>(
            x, mask, W1, b1, W2, b2, val_ws, pooled);
        finalize_kernel<<<B_, 256, 0, stream>>>(val_ws, pooled, W3, b3, out);
    }
}